// Round 15
// baseline (156.397 us; speedup 1.0000x reference)
//
#include <hip/hip_runtime.h>

#define BB 8
#define CC 256
#define HH 64
#define WW 64
#define RED 64
#define HW 4096   // HH*WW
#define AST 72    // xs bf16 row stride ([px][c] layout, 16B-aligned rows)
#define LSH 72    // bf16 LDS row stride (x1 / res planes in invol_dw)

typedef __attribute__((ext_vector_type(8))) short s8v;   // 8 bf16 (4 VGPRs)
typedef __attribute__((ext_vector_type(4))) float f4v;   // MFMA accumulator

__device__ __forceinline__ unsigned short f2bf(float f) {  // RNE f32->bf16
    unsigned u = __float_as_uint(f);
    u += 0x7fff + ((u >> 16) & 1);
    return (unsigned short)(u >> 16);
}
__device__ __forceinline__ float b2f(unsigned short u) {   // bf16->f32
    return __uint_as_float(((unsigned)u) << 16);
}

// ---- fused dwconv1 + involution-kernel-generation (half-row blocks) ----
// R15: R4-exact geometry/body EXCEPT loadB builds B-frags directly from
// w_red (f32, L2-resident) -- build_wtf kernel and its dispatch boundary
// are DELETED.  Rationale: R12's budget decomposition (dw measured 76)
// puts inter-dispatch gaps at ~13us/boundary; this removes one.  Cost:
// +2 float4 loads + 8 cvt per frag, issued AFTER the MFMA phase for the
// NEXT k-iter (latency-tolerant slot), into the same 16 live VGPRs (no
// R12 spill -- nothing extra is live across the k-loop).  R3 measured
// this loadB only at the old 512-thr geometry confounded with un-staged
// w_in; this round isolates it.
// [R7: 8 blk/CU regressed; R12: 16-frag register build spills; R10:
// device-scope sync ~200us; R1: coop launch fails under capture.
// Two-barrier k-loop -- do not re-pipeline.]
__global__ __launch_bounds__(256, 4) void dw_kern(const float* __restrict__ x,
                                                  const float* __restrict__ w_in,
                                                  const float* __restrict__ b_in,
                                                  const float* __restrict__ w_red,
                                                  const float* __restrict__ b_red,
                                                  const float* __restrict__ w_span,  // [9][64]
                                                  const float* __restrict__ b_span,
                                                  float* __restrict__ kern,
                                                  unsigned short* __restrict__ x1g) {
    alignas(16) __shared__ char smem[8448 + 12288];      // 20.25 KB
    unsigned short* xs = (unsigned short*)smem;          // [32px][AST] bf16 (4.6 KB)
    float* r_lds = (float*)smem;                         // [64o][33] f32, aliases xs (dead)
    float* wl    = (float*)(smem + 8448);                // [256c][12] w_in+b_in staging
    float* part  = (float*)(smem + 8448);                // [8og][9][32px], aliases wl (dead)

    const int t    = threadIdx.x;
    const int bx   = blockIdx.x;
    const int band = bx & 7;                     // XCD band swizzle
    const int idx  = bx >> 3;                    // 0..15
    const int h    = band * 8 + (idx >> 1);      // 8 consecutive h per XCD band
    const int wh   = idx & 1;                    // which 32-px half of the row
    const int b    = blockIdx.y;
    const int l  = t & 63;                       // lane
    const int wv = t >> 6;                       // wave 0..3
    const int mt = wv & 1, nh = wv >> 1;
    const int m0 = mt << 4;
    // phase-A mapping: 8 col-quads x 32 channel-rows
    const int q  = t & 7;
    const int pl = q << 2;                       // local px 0..28
    const int wg = (wh << 5) | pl;               // global w 0..60
    const int cr = t >> 3;                       // 0..31

    // stage w_in [256][9] + b_in [256] -> wl[c*12 + {0..8, 9}] (one-time)
    #pragma unroll
    for (int j = 0; j < 9; j++) {
        int i = j * 256 + t;                     // coalesced read of 2304 floats
        wl[(i / 9) * 12 + (i % 9)] = w_in[i];
    }
    wl[t * 12 + 9] = b_in[t];

    float4 pv[2][3]; float plf[2][3], prt[2][3]; // x-row prefetch regs

    auto loadX = [&](int c0) {
        #pragma unroll
        for (int s = 0; s < 2; s++) {
            const int cc = c0 + s * 32 + cr;
            const float* xp = x + ((size_t)(b * CC + cc)) * HW;
            #pragma unroll
            for (int ky = 0; ky < 3; ky++) {
                int hh = h + ky - 1;
                if (hh < 0 || hh >= HH) {        // block-uniform branch
                    pv[s][ky] = make_float4(0.f, 0.f, 0.f, 0.f);
                    plf[s][ky] = 0.f; prt[s][ky] = 0.f;
                    continue;
                }
                const float* row = xp + hh * WW + wg;
                pv[s][ky]  = *(const float4*)row;
                plf[s][ky] = (wg > 0)      ? row[-1] : 0.f;
                prt[s][ky] = (wg + 4 < WW) ? row[4]  : 0.f;
            }
        }
    };
    auto computeA = [&](int c0) {                // dwconv from regs -> bf16 xs + x1g
        #pragma unroll
        for (int s = 0; s < 2; s++) {
            const int cl = s * 32 + cr;
            const int cc = c0 + cl;
            const float* wp = wl + cc * 12;      // weights from LDS (staged once)
            float4 wa = *(const float4*)wp;      // w0..w3
            float4 wb = *(const float4*)(wp + 4);// w4..w7
            float2 wc = *(const float2*)(wp + 8);// w8, bias
            float4 a4 = make_float4(wc.y, wc.y, wc.y, wc.y);
            const float kw[9] = {wa.x, wa.y, wa.z, wa.w, wb.x, wb.y, wb.z, wb.w, wc.x};
            #pragma unroll
            for (int ky = 0; ky < 3; ky++) {
                float4 v = pv[s][ky];
                float lf = plf[s][ky], rt = prt[s][ky];
                float k0 = kw[ky * 3 + 0], k1 = kw[ky * 3 + 1], k2 = kw[ky * 3 + 2];
                a4.x = fmaf(k0, lf,  a4.x); a4.y = fmaf(k0, v.x, a4.y);
                a4.z = fmaf(k0, v.y, a4.z); a4.w = fmaf(k0, v.z, a4.w);
                a4.x = fmaf(k1, v.x, a4.x); a4.y = fmaf(k1, v.y, a4.y);
                a4.z = fmaf(k1, v.z, a4.z); a4.w = fmaf(k1, v.w, a4.w);
                a4.x = fmaf(k2, v.y, a4.x); a4.y = fmaf(k2, v.z, a4.y);
                a4.z = fmaf(k2, v.w, a4.z); a4.w = fmaf(k2, rt,  a4.w);
            }
            ushort4 pk;
            pk.x = f2bf(a4.x); pk.y = f2bf(a4.y);
            pk.z = f2bf(a4.z); pk.w = f2bf(a4.w);
            xs[(pl + 0) * AST + cl] = pk.x;      // [px][c] for A-frag reads
            xs[(pl + 1) * AST + cl] = pk.y;
            xs[(pl + 2) * AST + cl] = pk.z;
            xs[(pl + 3) * AST + cl] = pk.w;
            // bf16 x1 handoff for kernel 2
            *(ushort4*)(x1g + ((size_t)(b * CC + cc)) * HW + h * WW + wg) = pk;
        }
    };

    s8v bfr[2][2];                               // B-frags [kb][ntl] for current chunk
    auto loadB = [&](int k) {                    // direct from w_red (R15)
        #pragma unroll
        for (int kb = 0; kb < 2; kb++)
            #pragma unroll
            for (int ntl = 0; ntl < 2; ntl++) {
                // B[k][n] = w_red[o=n][c=k]; frag elem j contiguous in c
                const int o   = (((nh << 1) + ntl) << 4) + (l & 15);
                const int c0b = (((k << 1) + kb) << 5) + ((l >> 4) & 3) * 8;
                const float* wr = w_red + o * CC + c0b;
                float4 f0 = *(const float4*)wr;
                float4 f1 = *(const float4*)(wr + 4);
                s8v bv;
                bv[0] = (short)f2bf(f0.x); bv[1] = (short)f2bf(f0.y);
                bv[2] = (short)f2bf(f0.z); bv[3] = (short)f2bf(f0.w);
                bv[4] = (short)f2bf(f1.x); bv[5] = (short)f2bf(f1.y);
                bv[6] = (short)f2bf(f1.z); bv[7] = (short)f2bf(f1.w);
                bfr[kb][ntl] = bv;
            }
    };

    f4v acc[2] = {{0.f, 0.f, 0.f, 0.f}, {0.f, 0.f, 0.f, 0.f}};

    loadX(0); loadB(0);
    __syncthreads();                             // wl staged before computeA reads it
    for (int k = 0; k < 4; k++) {
        computeA(k << 6);                        // regs -> xs (bf16) + x1g
        if (k < 3) loadX((k + 1) << 6);          // VMEM issue for next chunk
        __syncthreads();
        // phase B: 2 A-frag ds_read_b128 + 4 MFMA per wave
        #pragma unroll
        for (int kb = 0; kb < 2; kb++) {
            const unsigned short* ap =
                xs + (m0 + (l & 15)) * AST + (kb << 5) + ((l >> 4) & 3) * 8;
            s8v av = *(const s8v*)ap;
            #pragma unroll
            for (int ntl = 0; ntl < 2; ntl++)
                acc[ntl] = __builtin_amdgcn_mfma_f32_16x16x32_bf16(
                    av, bfr[kb][ntl], acc[ntl], 0, 0, 0);
        }
        if (k < 3) loadB(k + 1);                 // post-MFMA latency-tolerant slot
        __syncthreads();                         // xs consumed; safe to overwrite
    }

    // C-frags -> r_lds[o][33] (aliases dead xs); D row = px, col = o
    #pragma unroll
    for (int ntl = 0; ntl < 2; ntl++) {
        int o = ((nh << 1) + ntl) * 16 + (l & 15);
        int pxr = m0 + ((l >> 4) & 3) * 4;       // row = (lane>>4)*4 + i
        #pragma unroll
        for (int i = 0; i < 4; i++)
            r_lds[o * 33 + pxr + i] = acc[ntl][i];
    }
    __syncthreads();

    // epilogue: relu + span contraction; og = t>>5 (8 o-groups of 8)
    const int px = t & 31;
    const int og = t >> 5;
    const int o0 = og << 3;
    float kk[9];
    #pragma unroll
    for (int j = 0; j < 9; j++) kk[j] = 0.f;
    #pragma unroll
    for (int i = 0; i < 8; i++) {
        float r = fmaxf(r_lds[(o0 + i) * 33 + px] + b_red[o0 + i], 0.f);
        #pragma unroll
        for (int j = 0; j < 9; j++) kk[j] = fmaf(w_span[j * RED + o0 + i], r, kk[j]);
    }
    __syncthreads();                             // wl dead -> part may overwrite
    #pragma unroll
    for (int j = 0; j < 9; j++) part[(og * 9 + j) * 32 + px] = kk[j];
    __syncthreads();

    // cross-o-group reduction: thread (px, jj) sums 8 partials for kern[jj]
    float* kp = kern + (size_t)b * 9 * HW + h * WW + (wh << 5) + px;
    const int jj = t >> 5;                       // 0..7
    {
        float s = b_span[jj];
        #pragma unroll
        for (int g = 0; g < 8; g++) s += part[(g * 9 + jj) * 32 + px];
        kp[jj * HW] = s;
    }
    if (t < 32) {                                // j = 8 by lanes 0..31
        float s = b_span[8];
        #pragma unroll
        for (int g = 0; g < 8; g++) s += part[(g * 9 + 8) * 32 + px];
        kp[8 * HW] = s;
    }
}

// ---- involution-apply + dwconv2, TWO c-planes per block ----
// [R14-exact -- best measured config: 137.7us total.]  kern loads shared
// across the (c, c+1) plane pair; accs in regs; bf16 res aliased into the
// dead x1 LDS.  LDS 18.4 KB; launch_bounds(256,4); grid (128,8)=1024.
__global__ __launch_bounds__(256, 4) void invol_dw(const unsigned short* __restrict__ x1g,
                                                   const float* __restrict__ kern,
                                                   const float* __restrict__ w_out,
                                                   const float* __restrict__ b_out,
                                                   float* __restrict__ out) {
    __shared__ unsigned short pln[2][HH * LSH];  // x1 planes, later res planes (18.4 KB)
    const int t  = threadIdx.x;
    const int q  = t & 15;
    const int w0 = q << 2;
    const int r  = t >> 4;                       // 0..15
    const int c0 = blockIdx.x << 1, b = blockIdx.y;

    // stage both x1 planes: 2 x 4096 bf16, fully contiguous
    {
        const int hl = t >> 2;                   // 0..63
        const int wl2 = (t & 3) << 4;            // 0,16,32,48
        #pragma unroll
        for (int p = 0; p < 2; p++) {
            const unsigned short* xp = x1g + ((size_t)(b * CC + c0 + p)) * HW;
            *(s8v*)&pln[p][hl * LSH + wl2]     = *(const s8v*)(xp + hl * WW + wl2);
            *(s8v*)&pln[p][hl * LSH + wl2 + 8] = *(const s8v*)(xp + hl * WW + wl2 + 8);
        }
    }
    __syncthreads();

    // involution, both planes, kern loads shared; accs in registers
    const float* kp = kern + (size_t)b * 9 * HW;
    float4 a0[4], a1[4];
    #pragma unroll
    for (int i = 0; i < 4; i++) {
        a0[i] = make_float4(0.f, 0.f, 0.f, 0.f);
        a1[i] = make_float4(0.f, 0.f, 0.f, 0.f);
    }
    #pragma unroll
    for (int i = 0; i < 4; i++) {
        int h  = r + (i << 4);
        int hw = h * WW + w0;
        #pragma unroll
        for (int ky = 0; ky < 3; ky++) {
            int hh = h + ky - 1;
            if (hh < 0 || hh >= HH) continue;    // zero patch
            float4 k0 = *(const float4*)(kp + (ky * 3 + 0) * HW + hw);
            float4 k1 = *(const float4*)(kp + (ky * 3 + 1) * HW + hw);
            float4 k2 = *(const float4*)(kp + (ky * 3 + 2) * HW + hw);
            #pragma unroll
            for (int p = 0; p < 2; p++) {        // static after unroll
                const unsigned short* row = &pln[p][hh * LSH + w0];
                float vx = b2f(row[0]), vy = b2f(row[1]);
                float vz = b2f(row[2]), vw = b2f(row[3]);
                float lf = (w0 > 0)      ? b2f(row[-1]) : 0.f;
                float rt = (w0 + 4 < WW) ? b2f(row[4])  : 0.f;
                float4& a = p ? a1[i] : a0[i];
                a.x = fmaf(k0.x, lf, a.x); a.y = fmaf(k0.y, vx, a.y);
                a.z = fmaf(k0.z, vy, a.z); a.w = fmaf(k0.w, vz, a.w);
                a.x = fmaf(k1.x, vx, a.x); a.y = fmaf(k1.y, vy, a.y);
                a.z = fmaf(k1.z, vz, a.z); a.w = fmaf(k1.w, vw, a.w);
                a.x = fmaf(k2.x, vy, a.x); a.y = fmaf(k2.y, vz, a.y);
                a.z = fmaf(k2.z, vw, a.z); a.w = fmaf(k2.w, rt, a.w);
            }
        }
    }
    __syncthreads();                             // all x1 reads complete

    // write bf16 res into the dead x1 space
    #pragma unroll
    for (int i = 0; i < 4; i++) {
        int h = r + (i << 4);
        ushort4 pk;
        pk.x = f2bf(a0[i].x); pk.y = f2bf(a0[i].y);
        pk.z = f2bf(a0[i].z); pk.w = f2bf(a0[i].w);
        *(ushort4*)&pln[0][h * LSH + w0] = pk;
        pk.x = f2bf(a1[i].x); pk.y = f2bf(a1[i].y);
        pk.z = f2bf(a1[i].z); pk.w = f2bf(a1[i].w);
        *(ushort4*)&pln[1][h * LSH + w0] = pk;
    }
    __syncthreads();                             // res visible to all threads

    // dwconv2, both planes, from bf16 res
    #pragma unroll
    for (int p = 0; p < 2; p++) {
        const float* wp = w_out + (c0 + p) * 9;  // block-uniform -> s_load
        const float bb = b_out[c0 + p];
        float* op = out + ((size_t)(b * CC + c0 + p)) * HW;
        #pragma unroll
        for (int i = 0; i < 4; i++) {
            int h = r + (i << 4);
            float4 acc = make_float4(bb, bb, bb, bb);
            #pragma unroll
            for (int ky = 0; ky < 3; ky++) {
                int hh = h + ky - 1;
                if (hh < 0 || hh >= HH) continue;
                const unsigned short* row = &pln[p][hh * LSH + w0];
                float vx = b2f(row[0]), vy = b2f(row[1]);
                float vz = b2f(row[2]), vw = b2f(row[3]);
                float lf = (w0 > 0)      ? b2f(row[-1]) : 0.f;
                float rt = (w0 + 4 < WW) ? b2f(row[4])  : 0.f;
                float k0 = wp[ky * 3 + 0], k1 = wp[ky * 3 + 1], k2 = wp[ky * 3 + 2];
                acc.x = fmaf(k0, lf, acc.x); acc.y = fmaf(k0, vx, acc.y);
                acc.z = fmaf(k0, vy, acc.z); acc.w = fmaf(k0, vz, acc.w);
                acc.x = fmaf(k1, vx, acc.x); acc.y = fmaf(k1, vy, acc.y);
                acc.z = fmaf(k1, vz, acc.z); acc.w = fmaf(k1, vw, acc.w);
                acc.x = fmaf(k2, vy, acc.x); acc.y = fmaf(k2, vz, acc.y);
                acc.z = fmaf(k2, vw, acc.z); acc.w = fmaf(k2, rt, acc.w);
            }
            *(float4*)(op + h * WW + w0) = acc;
        }
    }
}

extern "C" void kernel_launch(void* const* d_in, const int* in_sizes, int n_in,
                              void* d_out, int out_size, void* d_ws, size_t ws_size,
                              hipStream_t stream) {
    const float* x      = (const float*)d_in[0];
    const float* w_in   = (const float*)d_in[1];
    const float* b_in   = (const float*)d_in[2];
    const float* w_red  = (const float*)d_in[3];
    const float* b_red  = (const float*)d_in[4];
    const float* w_span = (const float*)d_in[5];
    const float* b_span = (const float*)d_in[6];
    const float* w_out  = (const float*)d_in[7];
    const float* b_out  = (const float*)d_in[8];
    float* out = (float*)d_out;

    float* kern = (float*)d_ws;                              // 1.18 MB
    unsigned short* x1g = (unsigned short*)(kern + (size_t)BB * 9 * HW); // 16.8 MB bf16

    dw_kern<<<dim3(128, BB), 256, 0, stream>>>(x, w_in, b_in, w_red, b_red,
                                               w_span, b_span, kern, x1g);
    invol_dw<<<dim3(CC / 2, BB), 256, 0, stream>>>(x1g, kern, w_out, b_out, out);
}

// Round 16
// 135.059 us; speedup vs baseline: 1.1580x; 1.1580x over previous
//
#include <hip/hip_runtime.h>

#define BB 8
#define CC 256
#define HH 64
#define WW 64
#define RED 64
#define HW 4096   // HH*WW
#define AST 72    // xs bf16 row stride ([px][c] layout, 16B-aligned rows)
#define LSH 72    // bf16 LDS row stride (x1 / res planes in invol_dw)

typedef __attribute__((ext_vector_type(8))) short s8v;   // 8 bf16 (4 VGPRs)
typedef __attribute__((ext_vector_type(4))) float f4v;   // MFMA accumulator

__device__ __forceinline__ unsigned short f2bf(float f) {  // RNE f32->bf16
    unsigned u = __float_as_uint(f);
    u += 0x7fff + ((u >> 16) & 1);
    return (unsigned short)(u >> 16);
}
__device__ __forceinline__ float b2f(unsigned short u) {   // bf16->f32
    return __uint_as_float(((unsigned)u) << 16);
}

// ---- build w_red in B-fragment order (bf16) ----
// wtf[e], e = ((kbg*4 + nt)*64 + lane)*8 + j  holds  B[k][n] = w_red[o=n][c=k].
// [R15 isolated: in-loop direct-from-w_red loadB costs ~+20us; R12: register
// build spills.  This 2us dispatch is the cheap form -- keep.]
__global__ __launch_bounds__(256) void build_wtf(const float* __restrict__ w_red,
                                                 unsigned short* __restrict__ wtf) {
    int e = blockIdx.x * 256 + threadIdx.x;      // 64 blocks -> 16384
    int j = e & 7, l = (e >> 3) & 63, nt = (e >> 9) & 3, kbg = e >> 11;
    int o = nt * 16 + (l & 15);
    int c = kbg * 32 + ((l >> 4) & 3) * 8 + j;
    wtf[e] = f2bf(w_red[o * CC + c]);
}

// ---- fused dwconv1 + involution-kernel-generation (half-row blocks) ----
// R16: R14-exact EXCEPT the x1g stores are DEFERRED out of the k-loop.
// Mechanism: __syncthreads' block memory-fence makes the compiler emit
// s_waitcnt vmcnt(0) before each barrier while global STORES are
// outstanding -- which also drains the just-issued loadX(k+1) prefetch
// (vmcnt counts loads+stores).  In-loop x1g stores thus defeat the
// prefetch at all 4 k-iterations.  Fix: hold the 8 ushort4 (16 VGPR,
// statically indexed via full k-unroll -- NOT an R12 spill repeat, total
// ~80 < 128 cap) and store after the loop, overlapping the epilogue.
// [R7: 8 blk/CU regressed; R10: device-scope sync ~200us; R1: coop launch
// fails under capture; R15: direct loadB +20us.]
__global__ __launch_bounds__(256, 4) void dw_kern(const float* __restrict__ x,
                                                  const float* __restrict__ w_in,
                                                  const float* __restrict__ b_in,
                                                  const unsigned short* __restrict__ wtf,
                                                  const float* __restrict__ b_red,
                                                  const float* __restrict__ w_span,  // [9][64]
                                                  const float* __restrict__ b_span,
                                                  float* __restrict__ kern,
                                                  unsigned short* __restrict__ x1g) {
    alignas(16) __shared__ char smem[8448 + 12288];      // 20.25 KB
    unsigned short* xs = (unsigned short*)smem;          // [32px][AST] bf16 (4.6 KB)
    float* r_lds = (float*)smem;                         // [64o][33] f32, aliases xs (dead)
    float* wl    = (float*)(smem + 8448);                // [256c][12] w_in+b_in staging
    float* part  = (float*)(smem + 8448);                // [8og][9][32px], aliases wl (dead)

    const int t    = threadIdx.x;
    const int bx   = blockIdx.x;
    const int band = bx & 7;                     // XCD band swizzle
    const int idx  = bx >> 3;                    // 0..15
    const int h    = band * 8 + (idx >> 1);      // 8 consecutive h per XCD band
    const int wh   = idx & 1;                    // which 32-px half of the row
    const int b    = blockIdx.y;
    const int l  = t & 63;                       // lane
    const int wv = t >> 6;                       // wave 0..3
    const int mt = wv & 1, nh = wv >> 1;
    const int m0 = mt << 4;
    // phase-A mapping: 8 col-quads x 32 channel-rows
    const int q  = t & 7;
    const int pl = q << 2;                       // local px 0..28
    const int wg = (wh << 5) | pl;               // global w 0..60
    const int cr = t >> 3;                       // 0..31

    // stage w_in [256][9] + b_in [256] -> wl[c*12 + {0..8, 9}] (one-time)
    #pragma unroll
    for (int j = 0; j < 9; j++) {
        int i = j * 256 + t;                     // coalesced read of 2304 floats
        wl[(i / 9) * 12 + (i % 9)] = w_in[i];
    }
    wl[t * 12 + 9] = b_in[t];

    float4 pv[2][3]; float plf[2][3], prt[2][3]; // x-row prefetch regs

    auto loadX = [&](int c0) {
        #pragma unroll
        for (int s = 0; s < 2; s++) {
            const int cc = c0 + s * 32 + cr;
            const float* xp = x + ((size_t)(b * CC + cc)) * HW;
            #pragma unroll
            for (int ky = 0; ky < 3; ky++) {
                int hh = h + ky - 1;
                if (hh < 0 || hh >= HH) {        // block-uniform branch
                    pv[s][ky] = make_float4(0.f, 0.f, 0.f, 0.f);
                    plf[s][ky] = 0.f; prt[s][ky] = 0.f;
                    continue;
                }
                const float* row = xp + hh * WW + wg;
                pv[s][ky]  = *(const float4*)row;
                plf[s][ky] = (wg > 0)      ? row[-1] : 0.f;
                prt[s][ky] = (wg + 4 < WW) ? row[4]  : 0.f;
            }
        }
    };
    auto computeA = [&](int c0, ushort4* pk_dst) {  // dwconv regs -> bf16 xs + regs
        #pragma unroll
        for (int s = 0; s < 2; s++) {
            const int cl = s * 32 + cr;
            const int cc = c0 + cl;
            const float* wp = wl + cc * 12;      // weights from LDS (staged once)
            float4 wa = *(const float4*)wp;      // w0..w3
            float4 wb = *(const float4*)(wp + 4);// w4..w7
            float2 wc = *(const float2*)(wp + 8);// w8, bias
            float4 a4 = make_float4(wc.y, wc.y, wc.y, wc.y);
            const float kw[9] = {wa.x, wa.y, wa.z, wa.w, wb.x, wb.y, wb.z, wb.w, wc.x};
            #pragma unroll
            for (int ky = 0; ky < 3; ky++) {
                float4 v = pv[s][ky];
                float lf = plf[s][ky], rt = prt[s][ky];
                float k0 = kw[ky * 3 + 0], k1 = kw[ky * 3 + 1], k2 = kw[ky * 3 + 2];
                a4.x = fmaf(k0, lf,  a4.x); a4.y = fmaf(k0, v.x, a4.y);
                a4.z = fmaf(k0, v.y, a4.z); a4.w = fmaf(k0, v.z, a4.w);
                a4.x = fmaf(k1, v.x, a4.x); a4.y = fmaf(k1, v.y, a4.y);
                a4.z = fmaf(k1, v.z, a4.z); a4.w = fmaf(k1, v.w, a4.w);
                a4.x = fmaf(k2, v.y, a4.x); a4.y = fmaf(k2, v.z, a4.y);
                a4.z = fmaf(k2, v.w, a4.z); a4.w = fmaf(k2, rt,  a4.w);
            }
            ushort4 pk;
            pk.x = f2bf(a4.x); pk.y = f2bf(a4.y);
            pk.z = f2bf(a4.z); pk.w = f2bf(a4.w);
            xs[(pl + 0) * AST + cl] = pk.x;      // [px][c] for A-frag reads
            xs[(pl + 1) * AST + cl] = pk.y;
            xs[(pl + 2) * AST + cl] = pk.z;
            xs[(pl + 3) * AST + cl] = pk.w;
            pk_dst[s] = pk;                      // DEFERRED x1g store (R16)
        }
    };

    s8v bfr[2][2];                               // B-frags [kb][ntl] for current chunk
    auto loadB = [&](int k) {
        #pragma unroll
        for (int kb = 0; kb < 2; kb++)
            #pragma unroll
            for (int ntl = 0; ntl < 2; ntl++) {
                int nt = (nh << 1) + ntl;
                int kbg = (k << 1) + kb;
                bfr[kb][ntl] = *(const s8v*)(wtf + (((kbg * 4 + nt) * 64 + l) << 3));
            }
    };

    f4v acc[2] = {{0.f, 0.f, 0.f, 0.f}, {0.f, 0.f, 0.f, 0.f}};
    ushort4 pk_sav[4][2];                        // 16 VGPR, static-indexed (unrolled)

    loadX(0); loadB(0);
    __syncthreads();                             // wl staged before computeA reads it
    #pragma unroll                               // full unroll: pk_sav indices static
    for (int k = 0; k < 4; k++) {
        computeA(k << 6, pk_sav[k]);             // regs -> xs (bf16) + pk_sav
        if (k < 3) loadX((k + 1) << 6);          // VMEM issue for next chunk
        __syncthreads();                         // no outstanding stores -> no drain
        // phase B: 2 A-frag ds_read_b128 + 4 MFMA per wave
        #pragma unroll
        for (int kb = 0; kb < 2; kb++) {
            const unsigned short* ap =
                xs + (m0 + (l & 15)) * AST + (kb << 5) + ((l >> 4) & 3) * 8;
            s8v av = *(const s8v*)ap;
            #pragma unroll
            for (int ntl = 0; ntl < 2; ntl++)
                acc[ntl] = __builtin_amdgcn_mfma_f32_16x16x32_bf16(
                    av, bfr[kb][ntl], acc[ntl], 0, 0, 0);
        }
        if (k < 3) loadB(k + 1);
        __syncthreads();                         // xs consumed; safe to overwrite
    }

    // deferred x1g stores: issue all 8 now; completion overlaps the epilogue
    #pragma unroll
    for (int k = 0; k < 4; k++)
        #pragma unroll
        for (int s = 0; s < 2; s++) {
            const int cc = (k << 6) + s * 32 + cr;
            *(ushort4*)(x1g + ((size_t)(b * CC + cc)) * HW + h * WW + wg) = pk_sav[k][s];
        }

    // C-frags -> r_lds[o][33] (aliases dead xs); D row = px, col = o
    #pragma unroll
    for (int ntl = 0; ntl < 2; ntl++) {
        int o = ((nh << 1) + ntl) * 16 + (l & 15);
        int pxr = m0 + ((l >> 4) & 3) * 4;       // row = (lane>>4)*4 + i
        #pragma unroll
        for (int i = 0; i < 4; i++)
            r_lds[o * 33 + pxr + i] = acc[ntl][i];
    }
    __syncthreads();

    // epilogue: relu + span contraction; og = t>>5 (8 o-groups of 8)
    const int px = t & 31;
    const int og = t >> 5;
    const int o0 = og << 3;
    float kk[9];
    #pragma unroll
    for (int j = 0; j < 9; j++) kk[j] = 0.f;
    #pragma unroll
    for (int i = 0; i < 8; i++) {
        float r = fmaxf(r_lds[(o0 + i) * 33 + px] + b_red[o0 + i], 0.f);
        #pragma unroll
        for (int j = 0; j < 9; j++) kk[j] = fmaf(w_span[j * RED + o0 + i], r, kk[j]);
    }
    __syncthreads();                             // wl dead -> part may overwrite
    #pragma unroll
    for (int j = 0; j < 9; j++) part[(og * 9 + j) * 32 + px] = kk[j];
    __syncthreads();

    // cross-o-group reduction: thread (px, jj) sums 8 partials for kern[jj]
    float* kp = kern + (size_t)b * 9 * HW + h * WW + (wh << 5) + px;
    const int jj = t >> 5;                       // 0..7
    {
        float s = b_span[jj];
        #pragma unroll
        for (int g = 0; g < 8; g++) s += part[(g * 9 + jj) * 32 + px];
        kp[jj * HW] = s;
    }
    if (t < 32) {                                // j = 8 by lanes 0..31
        float s = b_span[8];
        #pragma unroll
        for (int g = 0; g < 8; g++) s += part[(g * 9 + 8) * 32 + px];
        kp[8 * HW] = s;
    }
}

// ---- involution-apply + dwconv2, TWO c-planes per block ----
// [R14-exact -- best measured config: 137.7us total.]  kern loads shared
// across the (c, c+1) plane pair; accs in regs; bf16 res aliased into the
// dead x1 LDS.  LDS 18.4 KB; launch_bounds(256,4); grid (128,8)=1024.
__global__ __launch_bounds__(256, 4) void invol_dw(const unsigned short* __restrict__ x1g,
                                                   const float* __restrict__ kern,
                                                   const float* __restrict__ w_out,
                                                   const float* __restrict__ b_out,
                                                   float* __restrict__ out) {
    __shared__ unsigned short pln[2][HH * LSH];  // x1 planes, later res planes (18.4 KB)
    const int t  = threadIdx.x;
    const int q  = t & 15;
    const int w0 = q << 2;
    const int r  = t >> 4;                       // 0..15
    const int c0 = blockIdx.x << 1, b = blockIdx.y;

    // stage both x1 planes: 2 x 4096 bf16, fully contiguous
    {
        const int hl = t >> 2;                   // 0..63
        const int wl2 = (t & 3) << 4;            // 0,16,32,48
        #pragma unroll
        for (int p = 0; p < 2; p++) {
            const unsigned short* xp = x1g + ((size_t)(b * CC + c0 + p)) * HW;
            *(s8v*)&pln[p][hl * LSH + wl2]     = *(const s8v*)(xp + hl * WW + wl2);
            *(s8v*)&pln[p][hl * LSH + wl2 + 8] = *(const s8v*)(xp + hl * WW + wl2 + 8);
        }
    }
    __syncthreads();

    // involution, both planes, kern loads shared; accs in registers
    const float* kp = kern + (size_t)b * 9 * HW;
    float4 a0[4], a1[4];
    #pragma unroll
    for (int i = 0; i < 4; i++) {
        a0[i] = make_float4(0.f, 0.f, 0.f, 0.f);
        a1[i] = make_float4(0.f, 0.f, 0.f, 0.f);
    }
    #pragma unroll
    for (int i = 0; i < 4; i++) {
        int h  = r + (i << 4);
        int hw = h * WW + w0;
        #pragma unroll
        for (int ky = 0; ky < 3; ky++) {
            int hh = h + ky - 1;
            if (hh < 0 || hh >= HH) continue;    // zero patch
            float4 k0 = *(const float4*)(kp + (ky * 3 + 0) * HW + hw);
            float4 k1 = *(const float4*)(kp + (ky * 3 + 1) * HW + hw);
            float4 k2 = *(const float4*)(kp + (ky * 3 + 2) * HW + hw);
            #pragma unroll
            for (int p = 0; p < 2; p++) {        // static after unroll
                const unsigned short* row = &pln[p][hh * LSH + w0];
                float vx = b2f(row[0]), vy = b2f(row[1]);
                float vz = b2f(row[2]), vw = b2f(row[3]);
                float lf = (w0 > 0)      ? b2f(row[-1]) : 0.f;
                float rt = (w0 + 4 < WW) ? b2f(row[4])  : 0.f;
                float4& a = p ? a1[i] : a0[i];
                a.x = fmaf(k0.x, lf, a.x); a.y = fmaf(k0.y, vx, a.y);
                a.z = fmaf(k0.z, vy, a.z); a.w = fmaf(k0.w, vz, a.w);
                a.x = fmaf(k1.x, vx, a.x); a.y = fmaf(k1.y, vy, a.y);
                a.z = fmaf(k1.z, vz, a.z); a.w = fmaf(k1.w, vw, a.w);
                a.x = fmaf(k2.x, vy, a.x); a.y = fmaf(k2.y, vz, a.y);
                a.z = fmaf(k2.z, vw, a.z); a.w = fmaf(k2.w, rt, a.w);
            }
        }
    }
    __syncthreads();                             // all x1 reads complete

    // write bf16 res into the dead x1 space
    #pragma unroll
    for (int i = 0; i < 4; i++) {
        int h = r + (i << 4);
        ushort4 pk;
        pk.x = f2bf(a0[i].x); pk.y = f2bf(a0[i].y);
        pk.z = f2bf(a0[i].z); pk.w = f2bf(a0[i].w);
        *(ushort4*)&pln[0][h * LSH + w0] = pk;
        pk.x = f2bf(a1[i].x); pk.y = f2bf(a1[i].y);
        pk.z = f2bf(a1[i].z); pk.w = f2bf(a1[i].w);
        *(ushort4*)&pln[1][h * LSH + w0] = pk;
    }
    __syncthreads();                             // res visible to all threads

    // dwconv2, both planes, from bf16 res
    #pragma unroll
    for (int p = 0; p < 2; p++) {
        const float* wp = w_out + (c0 + p) * 9;  // block-uniform -> s_load
        const float bb = b_out[c0 + p];
        float* op = out + ((size_t)(b * CC + c0 + p)) * HW;
        #pragma unroll
        for (int i = 0; i < 4; i++) {
            int h = r + (i << 4);
            float4 acc = make_float4(bb, bb, bb, bb);
            #pragma unroll
            for (int ky = 0; ky < 3; ky++) {
                int hh = h + ky - 1;
                if (hh < 0 || hh >= HH) continue;
                const unsigned short* row = &pln[p][hh * LSH + w0];
                float vx = b2f(row[0]), vy = b2f(row[1]);
                float vz = b2f(row[2]), vw = b2f(row[3]);
                float lf = (w0 > 0)      ? b2f(row[-1]) : 0.f;
                float rt = (w0 + 4 < WW) ? b2f(row[4])  : 0.f;
                float k0 = wp[ky * 3 + 0], k1 = wp[ky * 3 + 1], k2 = wp[ky * 3 + 2];
                acc.x = fmaf(k0, lf, acc.x); acc.y = fmaf(k0, vx, acc.y);
                acc.z = fmaf(k0, vy, acc.z); acc.w = fmaf(k0, vz, acc.w);
                acc.x = fmaf(k1, vx, acc.x); acc.y = fmaf(k1, vy, acc.y);
                acc.z = fmaf(k1, vz, acc.z); acc.w = fmaf(k1, vw, acc.w);
                acc.x = fmaf(k2, vy, acc.x); acc.y = fmaf(k2, vz, acc.y);
                acc.z = fmaf(k2, vw, acc.z); acc.w = fmaf(k2, rt, acc.w);
            }
            *(float4*)(op + h * WW + w0) = acc;
        }
    }
}

extern "C" void kernel_launch(void* const* d_in, const int* in_sizes, int n_in,
                              void* d_out, int out_size, void* d_ws, size_t ws_size,
                              hipStream_t stream) {
    const float* x      = (const float*)d_in[0];
    const float* w_in   = (const float*)d_in[1];
    const float* b_in   = (const float*)d_in[2];
    const float* w_red  = (const float*)d_in[3];
    const float* b_red  = (const float*)d_in[4];
    const float* w_span = (const float*)d_in[5];
    const float* b_span = (const float*)d_in[6];
    const float* w_out  = (const float*)d_in[7];
    const float* b_out  = (const float*)d_in[8];
    float* out = (float*)d_out;

    float* kern = (float*)d_ws;                              // 1.18 MB
    unsigned short* x1g = (unsigned short*)(kern + (size_t)BB * 9 * HW); // 16.8 MB bf16
    unsigned short* wtf = x1g + (size_t)BB * CC * HW;        // 32 KB bf16

    build_wtf<<<64, 256, 0, stream>>>(w_red, wtf);
    dw_kern<<<dim3(128, BB), 256, 0, stream>>>(x, w_in, b_in, wtf, b_red,
                                               w_span, b_span, kern, x1g);
    invol_dw<<<dim3(CC / 2, BB), 256, 0, stream>>>(x1g, kern, w_out, b_out, out);
}